// Round 15
// baseline (120.036 us; speedup 1.0000x reference)
//
#include <hip/hip_runtime.h>

// MultiHeadAttentionForViTDiscriminator: B=4, C=1024, D=1024, H=16, DH=64
// R15: T3-minimum 2-phase double-buffering in all MFMA kernels:
//      stage(t+1) issued BEFORE compute(t), ONE barrier per K-step (loads in
//      flight across compute; correctness via compiler's auto vmcnt/lgkmcnt
//      drain at the barrier). attn: loads(t+1) -> compute(t) -> ds_write(t+1)
//      -> barrier. Inner math everywhere = R14-verified, numerics unchanged.
// Workspace (64 MB):
//   [0,8M) W16  [8,32M) X16 (Xq|Xk|Xv f16)  [32,40M) qb  [40,48M) kb
//   [48,56M) vTb  [56,64M) attnout
//   norms q2c2/k2c2 (2 x 256KB f32) live in d_out's head (dead before final GEMM).

typedef _Float16 f16;
typedef __attribute__((ext_vector_type(2))) _Float16 f16x2;
typedef __attribute__((ext_vector_type(8))) _Float16 f16x8;
typedef __attribute__((ext_vector_type(4))) float f32x4;
typedef __attribute__((ext_vector_type(16))) float f32x16;

#define MFMA16(a, b, c) __builtin_amdgcn_mfma_f32_16x16x32_f16((a), (b), (c), 0, 0, 0)
#define MFMA32(a, b, c) __builtin_amdgcn_mfma_f32_32x32x16_f16((a), (b), (c), 0, 0, 0)

constexpr double LOG2E = 1.4426950408889634;
constexpr double C2d = 0.015625 * LOG2E * LOG2E;  // (DH^-0.5 * log2e)^2

#if __has_builtin(__builtin_amdgcn_exp2f)
#define EXP2F(x) __builtin_amdgcn_exp2f(x)
#else
#define EXP2F(x) exp2f(x)
#endif
#if __has_builtin(__builtin_amdgcn_sqrtf)
#define SQRTF(x) __builtin_amdgcn_sqrtf(x)
#else
#define SQRTF(x) sqrtf(x)
#endif

__device__ __forceinline__ void stage16(const void* g, void* lds_base_uniform) {
#if __has_builtin(__builtin_amdgcn_global_load_lds)
    __builtin_amdgcn_global_load_lds((const __attribute__((address_space(1))) void*)g,
                                     (__attribute__((address_space(3))) void*)lds_base_uniform,
                                     16, 0, 0);
#else
    const int lane = threadIdx.x & 63;
    *(f16x8*)((f16*)lds_base_uniform + lane * 8) = *(const f16x8*)g;
#endif
}

__device__ __forceinline__ f16x8 cvt8v(f32x4 a, f32x4 b) {
    f16x8 o;
    o[0] = (f16)a[0]; o[1] = (f16)a[1]; o[2] = (f16)a[2]; o[3] = (f16)a[3];
    o[4] = (f16)b[0]; o[5] = (f16)b[1]; o[6] = (f16)b[2]; o[7] = (f16)b[3];
    return o;
}

// One conversion kernel for all fp32->f16 inputs. 8192 blocks x 2048 elems = 16M.
__global__ __launch_bounds__(256) void cvt_all(const float* __restrict__ Xq,
                                               const float* __restrict__ Xk,
                                               const float* __restrict__ Xv,
                                               const float* __restrict__ Wq,
                                               const float* __restrict__ Wk,
                                               const float* __restrict__ Wv,
                                               const float* __restrict__ Wp,
                                               f16* __restrict__ W16,
                                               f16* __restrict__ X16) {
    const size_t idx = (size_t)blockIdx.x * 2048 + threadIdx.x * 8;
    const size_t M4 = 4ull << 20, M1 = 1ull << 20;
    const float* s;
    f16* d;
    if (idx < 3 * M4) {
        if (idx < M4) s = Xq + idx;
        else if (idx < 2 * M4) s = Xk + (idx - M4);
        else s = Xv + (idx - 2 * M4);
        d = X16 + idx;
    } else {
        size_t wi = idx - 3 * M4;
        if (wi < M1) s = Wq + wi;
        else if (wi < 2 * M1) s = Wk + (wi - M1);
        else if (wi < 3 * M1) s = Wv + (wi - 2 * M1);
        else s = Wp + (wi - 3 * M1);
        d = W16 + wi;
    }
    f32x4 a = *(const f32x4*)s;
    f32x4 b = *(const f32x4*)(s + 4);
    *(f16x8*)d = cvt8v(a, b);
}

// 128x128 GEMM, 2-phase double-buffered (K=1024 fixed, 16 steps).
// 4 waves (2x2), 64x64 wave tile, MFMA32, XOR-swizzled LDS (R10-verified math).
template <bool NORMS, bool F32OUT>
__device__ __forceinline__ void gemm128_db(f16 (*As)[128 * 64], f16 (*Bs)[128 * 64],
                                           const f16* __restrict__ Ap,
                                           const f16* __restrict__ Bp,
                                           f16* __restrict__ Cop,
                                           float* __restrict__ Cf,
                                           const float* __restrict__ bias,
                                           float* __restrict__ nrmp,
                                           float osc, float nscale,
                                           int row0, int col0, int N) {
    const int tid = threadIdx.x;
    const int lane = tid & 63;
    const int w = tid >> 6;
    const int l31 = lane & 31, l5 = lane >> 5;
    const int wr = (w >> 1) * 64, wc = (w & 1) * 64;

    f32x16 acc[2][2] = {};

#define STAGE_AB(KT, BUF)                                                                \
    _Pragma("unroll") for (int t = 0; t < 4; ++t) {                                      \
        const int rb = w * 32 + t * 8;                                                   \
        const int rr = rb + (lane >> 3);                                                 \
        const int gs = (lane & 7) ^ (rr & 7);                                            \
        stage16(&Ap[(size_t)(row0 + rr) * 1024 + (KT) + gs * 8], &As[BUF][rb * 64]);     \
        stage16(&Bp[(size_t)(col0 + rr) * 1024 + (KT) + gs * 8], &Bs[BUF][rb * 64]);     \
    }

    STAGE_AB(0, 0)
    __syncthreads();
    for (int it = 0; it < 16; ++it) {
        const int cur = it & 1;
        if (it < 15) STAGE_AB((it + 1) * 64, cur ^ 1)  // in flight during compute
#pragma unroll
        for (int ks = 0; ks < 4; ++ks) {
            const int gq = ks * 2 + l5;
            f16x8 af[2], bf[2];
#pragma unroll
            for (int mr = 0; mr < 2; ++mr)
                af[mr] = *(const f16x8*)&As[cur][(wr + mr * 32 + l31) * 64 + ((gq ^ (l31 & 7)) * 8)];
#pragma unroll
            for (int n2 = 0; n2 < 2; ++n2)
                bf[n2] = *(const f16x8*)&Bs[cur][(wc + n2 * 32 + l31) * 64 + ((gq ^ (l31 & 7)) * 8)];
#pragma unroll
            for (int mr = 0; mr < 2; ++mr)
#pragma unroll
                for (int n2 = 0; n2 < 2; ++n2) acc[mr][n2] = MFMA32(af[mr], bf[n2], acc[mr][n2]);
        }
        __syncthreads();  // auto vmcnt/lgkm drain: next-tile loads landed, readers done
    }
#undef STAGE_AB

    const int cc0 = col0 + wc + l31;
    const int cc1 = col0 + wc + 32 + l31;
    const int hh = (col0 + wc) >> 6;
#pragma unroll
    for (int mr = 0; mr < 2; ++mr)
#pragma unroll
        for (int j = 0; j < 16; ++j) {
            const int rr = row0 + wr + mr * 32 + (j & 3) + 8 * (j >> 2) + 4 * l5;
            if (F32OUT) {
                Cf[(size_t)rr * N + cc0] = acc[mr][0][j] + bias[cc0];
                Cf[(size_t)rr * N + cc1] = acc[mr][1][j] + bias[cc1];
            } else {
                const f16 h0 = (f16)(acc[mr][0][j] * osc);
                const f16 h1 = (f16)(acc[mr][1][j] * osc);
                if (NORMS) {
                    float v0 = (float)h0, v1 = (float)h1;
                    float s = v0 * v0 + v1 * v1;
                    s += __shfl_xor(s, 1);
                    s += __shfl_xor(s, 2);
                    s += __shfl_xor(s, 4);
                    s += __shfl_xor(s, 8);
                    s += __shfl_xor(s, 16);
                    if (l31 == 0)
                        nrmp[(size_t)((rr >> 10) * 16 + hh) * 1024 + (rr & 1023)] = s * nscale;
                }
                Cop[(size_t)rr * N + cc0] = h0;
                Cop[(size_t)rr * N + cc1] = h1;
            }
        }
}

// Fused qk + vT launch, R14 L2 maps (qk: z=bid&1 XCD-specialized; vT chunked).
__global__ __launch_bounds__(256, 2) void gemm_qkv(const f16* __restrict__ X16,
                                                   const f16* __restrict__ W16,
                                                   f16* __restrict__ qb_base,
                                                   f16* __restrict__ vTb,
                                                   float* __restrict__ nrm,
                                                   float qsc, float ns_q, float ns_k) {
    __shared__ __attribute__((aligned(16))) f16 As[2][128 * 64];
    __shared__ __attribute__((aligned(16))) f16 Bs[2][128 * 64];
    const int bid = blockIdx.x;
    if (bid < 512) {
        const int z = bid & 1;
        const int t = (((bid & 7) >> 1) << 6) | (bid >> 3);
        const int row0 = (t >> 3) * 128;
        const int col0 = (t & 7) * 128;
        gemm128_db<true, false>(As, Bs,
                                X16 + (size_t)z * (4u << 20), W16 + (size_t)z * (1u << 20),
                                qb_base + (size_t)z * (4u << 20), nullptr, nullptr,
                                nrm + (size_t)z * 65536,
                                z ? 1.0f : qsc, z ? ns_k : ns_q, row0, col0, 1024);
    } else {
        const int f2 = bid - 512;
        const int x = f2 & 7, j = f2 >> 3;
        const int col0 = (x * 4 + (j & 3)) * 128;
        const int row0 = (j >> 2) * 128;
        gemm128_db<false, false>(As, Bs,
                                 W16 + 2 * (1u << 20), X16 + 2 * (4u << 20),
                                 vTb, nullptr, nullptr, nullptr,
                                 1.0f, 0.f, row0, col0, 4096);
    }
}

// Final projection: 64x128 tiles, 512 blocks, 2-phase double-buffered.
__global__ __launch_bounds__(256, 2) void gemm_fin(const f16* __restrict__ A,
                                                   const f16* __restrict__ B,
                                                   float* __restrict__ Cf,
                                                   const float* __restrict__ bias) {
    __shared__ __attribute__((aligned(16))) f16 As[2][64 * 64];
    __shared__ __attribute__((aligned(16))) f16 Bs[2][128 * 64];
    const int tid = threadIdx.x;
    const int lane = tid & 63;
    const int w = tid >> 6;
    const int l31 = lane & 31, l5 = lane >> 5;
    const int wr = (w & 1) * 32, wc = (w >> 1) * 64;
    const int f = blockIdx.x;
    const int g = (f & 7) * 64 + (f >> 3);
    const int row0 = (g >> 3) * 64, col0 = (g & 7) * 128;
    const int N = 1024;

    f32x16 acc[2] = {};

#define STAGE_FIN(KT, BUF)                                                               \
    _Pragma("unroll") for (int t = 0; t < 2; ++t) {                                      \
        const int rb = w * 16 + t * 8;                                                   \
        const int rr = rb + (lane >> 3);                                                 \
        const int gs = (lane & 7) ^ (rr & 7);                                            \
        stage16(&A[(size_t)(row0 + rr) * 1024 + (KT) + gs * 8], &As[BUF][rb * 64]);      \
    }                                                                                    \
    _Pragma("unroll") for (int t = 0; t < 4; ++t) {                                      \
        const int rb = w * 32 + t * 8;                                                   \
        const int rr = rb + (lane >> 3);                                                 \
        const int gs = (lane & 7) ^ (rr & 7);                                            \
        stage16(&B[(size_t)(col0 + rr) * 1024 + (KT) + gs * 8], &Bs[BUF][rb * 64]);      \
    }

    STAGE_FIN(0, 0)
    __syncthreads();
    for (int it = 0; it < 16; ++it) {
        const int cur = it & 1;
        if (it < 15) STAGE_FIN((it + 1) * 64, cur ^ 1)
#pragma unroll
        for (int ks = 0; ks < 4; ++ks) {
            const int gq = ks * 2 + l5;
            f16x8 af = *(const f16x8*)&As[cur][(wr + l31) * 64 + ((gq ^ (l31 & 7)) * 8)];
#pragma unroll
            for (int n2 = 0; n2 < 2; ++n2) {
                f16x8 bf = *(const f16x8*)&Bs[cur][(wc + n2 * 32 + l31) * 64 + ((gq ^ (l31 & 7)) * 8)];
                acc[n2] = MFMA32(af, bf, acc[n2]);
            }
        }
        __syncthreads();
    }
#undef STAGE_FIN

    const int cc0 = col0 + wc + l31;
    const int cc1 = col0 + wc + 32 + l31;
#pragma unroll
    for (int j = 0; j < 16; ++j) {
        const int rr = row0 + wr + (j & 3) + 8 * (j >> 2) + 4 * l5;
        Cf[(size_t)rr * N + cc0] = acc[0][j] + bias[cc0];
        Cf[(size_t)rr * N + cc1] = acc[1][j] + bias[cc1];
    }
}

// Distance attention: 1024 blocks x 256 threads, 64 q-rows/block, full-K loop.
// 2-phase double-buffered K/V/k2: loads(t+1) -> compute(t) -> ds_write(t+1) -> barrier.
// Inner compute = R14-verified (ping-pong K frags, hoisted V frags, in-reg P,
// ones-MFMA den).
__global__ __launch_bounds__(256, 2) void attn(const f16* __restrict__ qs,
                                               const f16* __restrict__ kb,
                                               const f16* __restrict__ vT,
                                               const float* __restrict__ q2c2,
                                               const float* __restrict__ k2c2,
                                               f16* __restrict__ out) {
    __shared__ __attribute__((aligned(16))) f16 Ks[2][128 * 64];  // permuted + swizzled
    __shared__ __attribute__((aligned(16))) f16 Vs[2][64 * 128];  // swizzled
    __shared__ float k2t[2][128];
    const int tid = threadIdx.x;
    const int lane = tid & 63;
    const int w = tid >> 6;
    const int l15 = lane & 15, l4 = lane >> 4;
    const int fid = blockIdx.y * 16 + blockIdx.x;
    const int qt = (fid >> 3) & 15;
    const int bh = (fid & 7) * 8 + (fid >> 7);
    const int b = bh >> 4, h = bh & 15;
    const int wq = w * 16;
    const int hcol = h * 64;
    const int qrow0 = b * 1024 + qt * 64;
    const f16* vTh = vT + (size_t)hcol * 4096 + b * 1024;  // vT[d=1024][tok=4096]

    const int sr = tid >> 3, sc0 = (tid & 7) * 8;   // K staging (keys sr+i*32)
    const int vr = tid >> 4, vc0 = (tid & 15) * 8;  // V staging (rows vr+j*16)
    const int vsw = (vr & 7) << 3;
    const int fsw = (l15 & 7) << 3;                 // fragment-read swizzle

    f16x8 bq[2];
#pragma unroll
    for (int ks = 0; ks < 2; ++ks)
        bq[ks] = *(const f16x8*)&qs[(size_t)(qrow0 + wq + l15) * 1024 + hcol + ks * 32 + l4 * 8];
    const float q2m = q2c2[(size_t)bh * 1024 + qt * 64 + wq + l15];

    f32x4 accv[4] = {};
    f32x4 dacc = {};
    const f16 one = (f16)1.f;
    const f16x8 ones8 = {one, one, one, one, one, one, one, one};

    f16x8 kreg[4], vreg[4];
    float k2reg = 0.f;
#define ISSUE_LOADS(KT)                                                                                      \
    {                                                                                                        \
        _Pragma("unroll") for (int i = 0; i < 4; ++i)                                                        \
            kreg[i] = *(const f16x8*)&kb[(size_t)(b * 1024 + (KT) * 128 + sr + i * 32) * 1024 + hcol + sc0]; \
        _Pragma("unroll") for (int j = 0; j < 4; ++j)                                                        \
            vreg[j] = *(const f16x8*)&vTh[(size_t)(vr + j * 16) * 4096 + (KT) * 128 + vc0];                  \
        k2reg = (tid < 128) ? k2c2[(size_t)bh * 1024 + (KT) * 128 + tid] : 0.f;                              \
    }
#define WRITE_TILE(BUF)                                                                                      \
    {                                                                                                        \
        _Pragma("unroll") for (int i = 0; i < 4; ++i) {                                                      \
            const int kap = sr + i * 32;                                                                     \
            const int s_ = ((kap >> 5) & 3) * 32 + ((kap >> 2) & 1) * 16 + ((kap >> 3) & 3) * 4 + (kap & 3); \
            *(f16x8*)&Ks[BUF][s_ * 64 + (sc0 ^ ((s_ & 7) << 3))] = kreg[i];                                  \
        }                                                                                                    \
        _Pragma("unroll") for (int j = 0; j < 4; ++j)                                                        \
            *(f16x8*)&Vs[BUF][(vr + j * 16) * 128 + (vc0 ^ vsw)] = vreg[j];                                  \
        if (tid < 128) k2t[BUF][tid] = k2reg;                                                                \
    }

    ISSUE_LOADS(0)
    WRITE_TILE(0)
    __syncthreads();

    for (int kt = 0; kt < 8; ++kt) {
        const int cur = kt & 1;
        if (kt < 7) ISSUE_LOADS(kt + 1)  // global loads in flight during compute

        // K-frag ping-pong: preload kk=0's two windows from buf[cur]
        f16x8 kfb[2][4];
#pragma unroll
        for (int hh = 0; hh < 2; ++hh) {
            kfb[0][hh * 2] = *(const f16x8*)&Ks[cur][(hh * 16 + l15) * 64 + ((l4 * 8) ^ fsw)];
            kfb[0][hh * 2 + 1] = *(const f16x8*)&Ks[cur][(hh * 16 + l15) * 64 + ((32 + l4 * 8) ^ fsw)];
        }
#pragma unroll
        for (int kk = 0; kk < 4; ++kk) {
            const int cb = kk & 1;
            if (kk < 3) {
#pragma unroll
                for (int hh = 0; hh < 2; ++hh) {
                    const int n_ = (kk + 1) * 2 + hh;
                    kfb[cb ^ 1][hh * 2] = *(const f16x8*)&Ks[cur][(n_ * 16 + l15) * 64 + ((l4 * 8) ^ fsw)];
                    kfb[cb ^ 1][hh * 2 + 1] = *(const f16x8*)&Ks[cur][(n_ * 16 + l15) * 64 + ((32 + l4 * 8) ^ fsw)];
                }
            }
            f16x8 vf[4];
#pragma unroll
            for (int n2 = 0; n2 < 4; ++n2)
                vf[n2] = *(const f16x8*)&Vs[cur][(n2 * 16 + l15) * 128 + ((kk * 32 + l4 * 8) ^ fsw)];

            unsigned um[4];
#pragma unroll
            for (int half = 0; half < 2; ++half) {
                f32x4 k2q = *(const f32x4*)&k2t[cur][kk * 32 + l4 * 8 + half * 4];
                f32x4 c0;
#pragma unroll
                for (int r = 0; r < 4; ++r) c0[r] = q2m + k2q[r];
                f32x4 st = MFMA16(kfb[cb][half * 2], bq[0], c0);
                st = MFMA16(kfb[cb][half * 2 + 1], bq[1], st);
                float p0 = EXP2F(SQRTF(fmaxf(st[0], 0.f)));
                float p1 = EXP2F(SQRTF(fmaxf(st[1], 0.f)));
                float p2 = EXP2F(SQRTF(fmaxf(st[2], 0.f)));
                float p3 = EXP2F(SQRTF(fmaxf(st[3], 0.f)));
                f16x2 lo = {(f16)p0, (f16)p1};
                f16x2 hi = {(f16)p2, (f16)p3};
                um[half * 2] = __builtin_bit_cast(unsigned, lo);
                um[half * 2 + 1] = __builtin_bit_cast(unsigned, hi);
            }
            uint4 u = {um[0], um[1], um[2], um[3]};
            f16x8 ap = __builtin_bit_cast(f16x8, u);
            dacc = MFMA16(ap, ones8, dacc);
#pragma unroll
            for (int n2 = 0; n2 < 4; ++n2) accv[n2] = MFMA16(ap, vf[n2], accv[n2]);
        }

        if (kt < 7) WRITE_TILE(cur ^ 1)  // buf free since prev barrier; regs landed
        __syncthreads();                 // drains ds_writes (lgkm) for next compute
    }
#undef ISSUE_LOADS
#undef WRITE_TILE

#pragma unroll
    for (int r = 0; r < 4; ++r) {
        const float rd = 1.0f / dacc[r];
#pragma unroll
        for (int n2 = 0; n2 < 4; ++n2)
            out[(size_t)(qrow0 + wq + l4 * 4 + r) * 1024 + hcol + n2 * 16 + l15] =
                (f16)(accv[n2][r] * rd);
    }
}

extern "C" void kernel_launch(void* const* d_in, const int* in_sizes, int n_in,
                              void* d_out, int out_size, void* d_ws, size_t ws_size,
                              hipStream_t stream) {
    const float* Xq = (const float*)d_in[0];
    const float* Xk = (const float*)d_in[1];
    const float* Xv = (const float*)d_in[2];
    const float* Wq = (const float*)d_in[3];
    const float* Wk = (const float*)d_in[4];
    const float* Wv = (const float*)d_in[5];
    const float* Wp = (const float*)d_in[6];
    const float* bp = (const float*)d_in[7];
    float* out = (float*)d_out;

    char* ws = (char*)d_ws;
    f16* W16 = (f16*)(ws);                      // 4M f16
    f16* X16 = (f16*)(ws + (8ull << 20));       // Xq16|Xk16|Xv16
    f16* qb = (f16*)(ws + (32ull << 20));       // qk out base (z-stride 4M f16)
    f16* kb = (f16*)(ws + (40ull << 20));
    f16* vTb = (f16*)(ws + (48ull << 20));
    f16* attnout = (f16*)(ws + (56ull << 20));
    (void)kb;
    // norms scratch in d_out head; written each launch before use, overwritten by final GEMM
    float* q2c2 = out;
    float* k2c2 = out + 65536;

    const float qsc = (float)(-2.0 * C2d);
    const float ns_q = (float)(1.0 / (4.0 * C2d));
    const float ns_k = (float)C2d;

    cvt_all<<<8192, 256, 0, stream>>>(Xq, Xk, Xv, Wq, Wk, Wv, Wp, W16, X16);

    // fused q-proj + k-proj + vT (768 blocks)
    gemm_qkv<<<768, 256, 0, stream>>>(X16, W16, qb, vTb, q2c2, qsc, ns_q, ns_k);

    attn<<<dim3(16, 64), 256, 0, stream>>>(qb, kb, vTb, q2c2, k2c2, attnout);

    gemm_fin<<<512, 256, 0, stream>>>(attnout, W16 + 3 * (1u << 20), out, bp);
}

// Round 16
// 107.635 us; speedup vs baseline: 1.1152x; 1.1152x over previous
//
#include <hip/hip_runtime.h>

// MultiHeadAttentionForViTDiscriminator: B=4, C=1024, D=1024, H=16, DH=64
// R16: revert R15's 2-phase dbuf everywhere (regressed: +17us; single-barrier
//      drain + doubled LDS cost a resident block -- matches m99/m100's "dbuf
//      neutral at best" on this structure). Base = R14 (verified 102.8us,
//      FETCH-validated L2 maps). One change: attn DISTANCE-2 global prefetch
//      via two named register banks (A=even tiles, B=odd) -- R14's dist-1 gave
//      ~700cy slack vs ~900cy HBM latency; dist-2 gives ~1500cy, and bank-B
//      loads staying in flight across bank-A's drain yields counted vmcnt (T4).
// Workspace (64 MB):
//   [0,8M) W16  [8,32M) X16 (Xq|Xk|Xv f16)  [32,40M) qb  [40,48M) kb
//   [48,56M) vTb  [56,64M) attnout
//   norms q2c2/k2c2 (2 x 256KB f32) live in d_out's head (dead before final GEMM).

typedef _Float16 f16;
typedef __attribute__((ext_vector_type(2))) _Float16 f16x2;
typedef __attribute__((ext_vector_type(8))) _Float16 f16x8;
typedef __attribute__((ext_vector_type(4))) float f32x4;
typedef __attribute__((ext_vector_type(16))) float f32x16;

#define MFMA16(a, b, c) __builtin_amdgcn_mfma_f32_16x16x32_f16((a), (b), (c), 0, 0, 0)
#define MFMA32(a, b, c) __builtin_amdgcn_mfma_f32_32x32x16_f16((a), (b), (c), 0, 0, 0)

constexpr double LOG2E = 1.4426950408889634;
constexpr double C2d = 0.015625 * LOG2E * LOG2E;  // (DH^-0.5 * log2e)^2

#if __has_builtin(__builtin_amdgcn_exp2f)
#define EXP2F(x) __builtin_amdgcn_exp2f(x)
#else
#define EXP2F(x) exp2f(x)
#endif
#if __has_builtin(__builtin_amdgcn_sqrtf)
#define SQRTF(x) __builtin_amdgcn_sqrtf(x)
#else
#define SQRTF(x) sqrtf(x)
#endif

__device__ __forceinline__ void stage16(const void* g, void* lds_base_uniform) {
#if __has_builtin(__builtin_amdgcn_global_load_lds)
    __builtin_amdgcn_global_load_lds((const __attribute__((address_space(1))) void*)g,
                                     (__attribute__((address_space(3))) void*)lds_base_uniform,
                                     16, 0, 0);
#else
    const int lane = threadIdx.x & 63;
    *(f16x8*)((f16*)lds_base_uniform + lane * 8) = *(const f16x8*)g;
#endif
}

__device__ __forceinline__ f16x8 cvt8v(f32x4 a, f32x4 b) {
    f16x8 o;
    o[0] = (f16)a[0]; o[1] = (f16)a[1]; o[2] = (f16)a[2]; o[3] = (f16)a[3];
    o[4] = (f16)b[0]; o[5] = (f16)b[1]; o[6] = (f16)b[2]; o[7] = (f16)b[3];
    return o;
}

// One conversion kernel for all fp32->f16 inputs. 8192 blocks x 2048 elems = 16M.
__global__ __launch_bounds__(256) void cvt_all(const float* __restrict__ Xq,
                                               const float* __restrict__ Xk,
                                               const float* __restrict__ Xv,
                                               const float* __restrict__ Wq,
                                               const float* __restrict__ Wk,
                                               const float* __restrict__ Wv,
                                               const float* __restrict__ Wp,
                                               f16* __restrict__ W16,
                                               f16* __restrict__ X16) {
    const size_t idx = (size_t)blockIdx.x * 2048 + threadIdx.x * 8;
    const size_t M4 = 4ull << 20, M1 = 1ull << 20;
    const float* s;
    f16* d;
    if (idx < 3 * M4) {
        if (idx < M4) s = Xq + idx;
        else if (idx < 2 * M4) s = Xk + (idx - M4);
        else s = Xv + (idx - 2 * M4);
        d = X16 + idx;
    } else {
        size_t wi = idx - 3 * M4;
        if (wi < M1) s = Wq + wi;
        else if (wi < 2 * M1) s = Wk + (wi - M1);
        else if (wi < 3 * M1) s = Wv + (wi - 2 * M1);
        else s = Wp + (wi - 3 * M1);
        d = W16 + wi;
    }
    f32x4 a = *(const f32x4*)s;
    f32x4 b = *(const f32x4*)(s + 4);
    *(f16x8*)d = cvt8v(a, b);
}

// 128x128 GEMM body (R10-verified): BK=64, 4 waves (2x2), 64x64 wave tile,
// MFMA32, XOR-swizzled LDS via pre-swizzled gload_lds source. Single-buffered
// (R15 dbuf regressed).
template <bool NORMS, bool F32OUT>
__device__ __forceinline__ void gemm128(f16* As, f16* Bs,
                                        const f16* __restrict__ Ap,
                                        const f16* __restrict__ Bp,
                                        f16* __restrict__ Cop,
                                        float* __restrict__ Cf,
                                        const float* __restrict__ bias,
                                        float* __restrict__ nrmp,
                                        float osc, float nscale,
                                        int row0, int col0, int N, int K) {
    const int tid = threadIdx.x;
    const int lane = tid & 63;
    const int w = tid >> 6;
    const int l31 = lane & 31, l5 = lane >> 5;
    const int wr = (w >> 1) * 64, wc = (w & 1) * 64;

    f32x16 acc[2][2] = {};

    for (int kt = 0; kt < K; kt += 64) {
        __syncthreads();
#pragma unroll
        for (int t = 0; t < 4; ++t) {
            const int rb = w * 32 + t * 8;
            const int rr = rb + (lane >> 3);
            const int gs = (lane & 7) ^ (rr & 7);
            stage16(&Ap[(size_t)(row0 + rr) * K + kt + gs * 8], &As[rb * 64]);
            stage16(&Bp[(size_t)(col0 + rr) * K + kt + gs * 8], &Bs[rb * 64]);
        }
        __syncthreads();
#pragma unroll
        for (int ks = 0; ks < 4; ++ks) {
            const int gq = ks * 2 + l5;
            f16x8 af[2], bf[2];
#pragma unroll
            for (int mr = 0; mr < 2; ++mr)
                af[mr] = *(const f16x8*)&As[(wr + mr * 32 + l31) * 64 + ((gq ^ (l31 & 7)) * 8)];
#pragma unroll
            for (int n2 = 0; n2 < 2; ++n2)
                bf[n2] = *(const f16x8*)&Bs[(wc + n2 * 32 + l31) * 64 + ((gq ^ (l31 & 7)) * 8)];
#pragma unroll
            for (int mr = 0; mr < 2; ++mr)
#pragma unroll
                for (int n2 = 0; n2 < 2; ++n2) acc[mr][n2] = MFMA32(af[mr], bf[n2], acc[mr][n2]);
        }
    }

    const int cc0 = col0 + wc + l31;
    const int cc1 = col0 + wc + 32 + l31;
    const int hh = (col0 + wc) >> 6;
#pragma unroll
    for (int mr = 0; mr < 2; ++mr)
#pragma unroll
        for (int j = 0; j < 16; ++j) {
            const int rr = row0 + wr + mr * 32 + (j & 3) + 8 * (j >> 2) + 4 * l5;
            if (F32OUT) {
                Cf[(size_t)rr * N + cc0] = acc[mr][0][j] + bias[cc0];
                Cf[(size_t)rr * N + cc1] = acc[mr][1][j] + bias[cc1];
            } else {
                const f16 h0 = (f16)(acc[mr][0][j] * osc);
                const f16 h1 = (f16)(acc[mr][1][j] * osc);
                if (NORMS) {
                    float v0 = (float)h0, v1 = (float)h1;
                    float s = v0 * v0 + v1 * v1;
                    s += __shfl_xor(s, 1);
                    s += __shfl_xor(s, 2);
                    s += __shfl_xor(s, 4);
                    s += __shfl_xor(s, 8);
                    s += __shfl_xor(s, 16);
                    if (l31 == 0)
                        nrmp[(size_t)((rr >> 10) * 16 + hh) * 1024 + (rr & 1023)] = s * nscale;
                }
                Cop[(size_t)rr * N + cc0] = h0;
                Cop[(size_t)rr * N + cc1] = h1;
            }
        }
}

// Fused qk + vT launch with XCD-aware mappings (dispatch round-robins bid%8):
//   qk (bid<512): z = bid&1 -> each XCD runs only q or k (4MB/XCD <= L2).
//   vT (bid>=512): 4 token-col strips x all 8 Wv rows per XCD (3MB <= L2).
// (FETCH 58.5->28.8MB validated by R15's counter row.)
__global__ __launch_bounds__(256, 2) void gemm_qkv(const f16* __restrict__ X16,
                                                   const f16* __restrict__ W16,
                                                   f16* __restrict__ qb_base,
                                                   f16* __restrict__ vTb,
                                                   float* __restrict__ nrm,
                                                   float qsc, float ns_q, float ns_k) {
    __shared__ __attribute__((aligned(16))) f16 As[128 * 64];
    __shared__ __attribute__((aligned(16))) f16 Bs[128 * 64];
    const int bid = blockIdx.x;
    if (bid < 512) {
        const int z = bid & 1;
        const int t = (((bid & 7) >> 1) << 6) | (bid >> 3);  // bijective per z
        const int row0 = (t >> 3) * 128;
        const int col0 = (t & 7) * 128;
        gemm128<true, false>(As, Bs,
                             X16 + (size_t)z * (4u << 20), W16 + (size_t)z * (1u << 20),
                             qb_base + (size_t)z * (4u << 20), nullptr, nullptr,
                             nrm + (size_t)z * 65536,
                             z ? 1.0f : qsc, z ? ns_k : ns_q, row0, col0, 1024, 1024);
    } else {
        const int f2 = bid - 512;
        const int x = f2 & 7, j = f2 >> 3;
        const int col0 = (x * 4 + (j & 3)) * 128;
        const int row0 = (j >> 2) * 128;
        gemm128<false, false>(As, Bs,
                              W16 + 2 * (1u << 20), X16 + 2 * (4u << 20),
                              vTb, nullptr, nullptr, nullptr,
                              1.0f, 0.f, row0, col0, 4096, 1024);
    }
}

// Final projection: 64x128 tiles, 512 blocks (2/CU). f32 out + bias.
__global__ __launch_bounds__(256, 2) void gemm_fin(const f16* __restrict__ A,
                                                   const f16* __restrict__ B,
                                                   float* __restrict__ Cf,
                                                   const float* __restrict__ bias) {
    __shared__ __attribute__((aligned(16))) f16 As[64 * 64];
    __shared__ __attribute__((aligned(16))) f16 Bs[128 * 64];
    const int tid = threadIdx.x;
    const int lane = tid & 63;
    const int w = tid >> 6;
    const int l31 = lane & 31, l5 = lane >> 5;
    const int wr = (w & 1) * 32, wc = (w >> 1) * 64;
    const int f = blockIdx.x;
    const int g = (f & 7) * 64 + (f >> 3);
    const int row0 = (g >> 3) * 64, col0 = (g & 7) * 128;
    const int K = 1024, N = 1024;

    f32x16 acc[2] = {};

    for (int kt = 0; kt < K; kt += 64) {
        __syncthreads();
#pragma unroll
        for (int t = 0; t < 2; ++t) {  // A: 64 rows
            const int rb = w * 16 + t * 8;
            const int rr = rb + (lane >> 3);
            const int gs = (lane & 7) ^ (rr & 7);
            stage16(&A[(size_t)(row0 + rr) * K + kt + gs * 8], &As[rb * 64]);
        }
#pragma unroll
        for (int t = 0; t < 4; ++t) {  // B: 128 rows
            const int rb = w * 32 + t * 8;
            const int rr = rb + (lane >> 3);
            const int gs = (lane & 7) ^ (rr & 7);
            stage16(&B[(size_t)(col0 + rr) * K + kt + gs * 8], &Bs[rb * 64]);
        }
        __syncthreads();
#pragma unroll
        for (int ks = 0; ks < 4; ++ks) {
            const int gq = ks * 2 + l5;
            f16x8 af = *(const f16x8*)&As[(wr + l31) * 64 + ((gq ^ (l31 & 7)) * 8)];
#pragma unroll
            for (int n2 = 0; n2 < 2; ++n2) {
                f16x8 bf = *(const f16x8*)&Bs[(wc + n2 * 32 + l31) * 64 + ((gq ^ (l31 & 7)) * 8)];
                acc[n2] = MFMA32(af, bf, acc[n2]);
            }
        }
    }

    const int cc0 = col0 + wc + l31;
    const int cc1 = col0 + wc + 32 + l31;
#pragma unroll
    for (int j = 0; j < 16; ++j) {
        const int rr = row0 + wr + (j & 3) + 8 * (j >> 2) + 4 * l5;
        Cf[(size_t)rr * N + cc0] = acc[0][j] + bias[cc0];
        Cf[(size_t)rr * N + cc1] = acc[1][j] + bias[cc1];
    }
}

// Distance attention: 1024 blocks x 256 threads, 64 q-rows/block, full-K loop.
// Single-buffered LDS (R14); DISTANCE-2 global prefetch via named reg banks
// A (even tiles) / B (odd tiles). Inner compute = R14-verified.
__global__ __launch_bounds__(256, 2) void attn(const f16* __restrict__ qs,
                                               const f16* __restrict__ kb,
                                               const f16* __restrict__ vT,
                                               const float* __restrict__ q2c2,
                                               const float* __restrict__ k2c2,
                                               f16* __restrict__ out) {
    __shared__ __attribute__((aligned(16))) f16 Ks[128 * 64];  // permuted slots + XOR swizzle
    __shared__ __attribute__((aligned(16))) f16 Vs[64 * 128];  // XOR-swizzled
    __shared__ float k2tile[128];                              // linear (keyed by true k)
    const int tid = threadIdx.x;
    const int lane = tid & 63;
    const int w = tid >> 6;
    const int l15 = lane & 15, l4 = lane >> 4;
    const int fid = blockIdx.y * 16 + blockIdx.x;
    const int qt = (fid >> 3) & 15;
    const int bh = (fid & 7) * 8 + (fid >> 7);
    const int b = bh >> 4, h = bh & 15;
    const int wq = w * 16;
    const int hcol = h * 64;
    const int qrow0 = b * 1024 + qt * 64;
    const f16* vTh = vT + (size_t)hcol * 4096 + b * 1024;  // vT[d=1024][tok=4096]

    const int sr = tid >> 3, sc0 = (tid & 7) * 8;   // K staging (keys sr+i*32)
    const int vr = tid >> 4, vc0 = (tid & 15) * 8;  // V staging (rows vr+j*16)
    const int vsw = (vr & 7) << 3;
    const int fsw = (l15 & 7) << 3;                 // fragment-read swizzle

    f16x8 bq[2];
#pragma unroll
    for (int ks = 0; ks < 2; ++ks)
        bq[ks] = *(const f16x8*)&qs[(size_t)(qrow0 + wq + l15) * 1024 + hcol + ks * 32 + l4 * 8];
    const float q2m = q2c2[(size_t)bh * 1024 + qt * 64 + wq + l15];

    f32x4 accv[4] = {};
    f32x4 dacc = {};
    const f16 one = (f16)1.f;
    const f16x8 ones8 = {one, one, one, one, one, one, one, one};

    // Two named register banks: A = even tiles, B = odd tiles (no runtime indexing).
    f16x8 kregA[4], vregA[4], kregB[4], vregB[4];
    float k2regA = 0.f, k2regB = 0.f;
#define ISSUE_BANK(KT, KR, VR, K2)                                                                           \
    {                                                                                                        \
        _Pragma("unroll") for (int i = 0; i < 4; ++i)                                                        \
            KR[i] = *(const f16x8*)&kb[(size_t)(b * 1024 + (KT) * 128 + sr + i * 32) * 1024 + hcol + sc0];   \
        _Pragma("unroll") for (int j = 0; j < 4; ++j)                                                        \
            VR[j] = *(const f16x8*)&vTh[(size_t)(vr + j * 16) * 4096 + (KT) * 128 + vc0];                    \
        K2 = (tid < 128) ? k2c2[(size_t)bh * 1024 + (KT) * 128 + tid] : 0.f;                                 \
    }
#define WRITE_BANK(KR, VR, K2)                                                                               \
    {                                                                                                        \
        _Pragma("unroll") for (int i = 0; i < 4; ++i) {                                                      \
            const int kap = sr + i * 32;                                                                     \
            const int s_ = ((kap >> 5) & 3) * 32 + ((kap >> 2) & 1) * 16 + ((kap >> 3) & 3) * 4 + (kap & 3); \
            *(f16x8*)&Ks[s_ * 64 + (sc0 ^ ((s_ & 7) << 3))] = KR[i];                                         \
        }                                                                                                    \
        _Pragma("unroll") for (int j = 0; j < 4; ++j)                                                        \
            *(f16x8*)&Vs[(vr + j * 16) * 128 + (vc0 ^ vsw)] = VR[j];                                         \
        if (tid < 128) k2tile[tid] = K2;                                                                     \
    }

    ISSUE_BANK(0, kregA, vregA, k2regA)  // tile 0 -> bank A
    ISSUE_BANK(1, kregB, vregB, k2regB)  // tile 1 -> bank B (stays in flight across A's drain)

    for (int kt = 0; kt < 8; ++kt) {
        __syncthreads();  // prev-tile readers done
        if ((kt & 1) == 0) WRITE_BANK(kregA, vregA, k2regA)
        else               WRITE_BANK(kregB, vregB, k2regB)
        __syncthreads();  // writes visible
        if (kt < 6) {     // distance-2 prefetch into the bank just consumed
            if ((kt & 1) == 0) ISSUE_BANK(kt + 2, kregA, vregA, k2regA)
            else               ISSUE_BANK(kt + 2, kregB, vregB, k2regB)
        }

        // K-frag ping-pong: preload kk=0's two windows
        f16x8 kfb[2][4];
#pragma unroll
        for (int hh = 0; hh < 2; ++hh) {
            kfb[0][hh * 2] = *(const f16x8*)&Ks[(hh * 16 + l15) * 64 + ((l4 * 8) ^ fsw)];
            kfb[0][hh * 2 + 1] = *(const f16x8*)&Ks[(hh * 16 + l15) * 64 + ((32 + l4 * 8) ^ fsw)];
        }
#pragma unroll
        for (int kk = 0; kk < 4; ++kk) {
            const int cb = kk & 1;
            if (kk < 3) {
#pragma unroll
                for (int hh = 0; hh < 2; ++hh) {
                    const int n_ = (kk + 1) * 2 + hh;
                    kfb[cb ^ 1][hh * 2] = *(const f16x8*)&Ks[(n_ * 16 + l15) * 64 + ((l4 * 8) ^ fsw)];
                    kfb[cb ^ 1][hh * 2 + 1] = *(const f16x8*)&Ks[(n_ * 16 + l15) * 64 + ((32 + l4 * 8) ^ fsw)];
                }
            }
            // V frags issued before the trans chain
            f16x8 vf[4];
#pragma unroll
            for (int n2 = 0; n2 < 4; ++n2)
                vf[n2] = *(const f16x8*)&Vs[(n2 * 16 + l15) * 128 + ((kk * 32 + l4 * 8) ^ fsw)];

            unsigned um[4];
#pragma unroll
            for (int half = 0; half < 2; ++half) {
                f32x4 k2q = *(const f32x4*)&k2tile[kk * 32 + l4 * 8 + half * 4];
                f32x4 c0;
#pragma unroll
                for (int r = 0; r < 4; ++r) c0[r] = q2m + k2q[r];
                f32x4 st = MFMA16(kfb[cb][half * 2], bq[0], c0);
                st = MFMA16(kfb[cb][half * 2 + 1], bq[1], st);
                float p0 = EXP2F(SQRTF(fmaxf(st[0], 0.f)));
                float p1 = EXP2F(SQRTF(fmaxf(st[1], 0.f)));
                float p2 = EXP2F(SQRTF(fmaxf(st[2], 0.f)));
                float p3 = EXP2F(SQRTF(fmaxf(st[3], 0.f)));
                f16x2 lo = {(f16)p0, (f16)p1};
                f16x2 hi = {(f16)p2, (f16)p3};
                um[half * 2] = __builtin_bit_cast(unsigned, lo);
                um[half * 2 + 1] = __builtin_bit_cast(unsigned, hi);
            }
            uint4 u = {um[0], um[1], um[2], um[3]};
            f16x8 ap = __builtin_bit_cast(f16x8, u);
            dacc = MFMA16(ap, ones8, dacc);
#pragma unroll
            for (int n2 = 0; n2 < 4; ++n2) accv[n2] = MFMA16(ap, vf[n2], accv[n2]);
        }
    }
#undef ISSUE_BANK
#undef WRITE_BANK

#pragma unroll
    for (int r = 0; r < 4; ++r) {
        const float rd = 1.0f / dacc[r];
#pragma unroll
        for (int n2 = 0; n2 < 4; ++n2)
            out[(size_t)(qrow0 + wq + l4 * 4 + r) * 1024 + hcol + n2 * 16 + l15] =
                (f16)(accv[n2][r] * rd);
    }
}

extern "C" void kernel_launch(void* const* d_in, const int* in_sizes, int n_in,
                              void* d_out, int out_size, void* d_ws, size_t ws_size,
                              hipStream_t stream) {
    const float* Xq = (const float*)d_in[0];
    const float* Xk = (const float*)d_in[1];
    const float* Xv = (const float*)d_in[2];
    const float* Wq = (const float*)d_in[3];
    const float* Wk = (const float*)d_in[4];
    const float* Wv = (const float*)d_in[5];
    const float* Wp = (const float*)d_in[6];
    const float* bp = (const float*)d_in[7];
    float* out = (float*)d_out;

    char* ws = (char*)d_ws;
    f16* W16 = (f16*)(ws);                      // 4M f16
    f16* X16 = (f16*)(ws + (8ull << 20));       // Xq16|Xk16|Xv16
    f16* qb = (f16*)(ws + (32ull << 20));       // qk out base (z-stride 4M f16)
    f16* kb = (f16*)(ws + (40ull << 20));
    f16* vTb = (f16*)(ws + (48ull << 20));
    f16* attnout = (f16*)(ws + (56ull << 20));
    (void)kb;
    // norms scratch in d_out head; written each launch before use, overwritten by final GEMM
    float* q2c2 = out;
    float* k2c2 = out + 65536;

    const float qsc = (float)(-2.0 * C2d);
    const float ns_q = (float)(1.0 / (4.0 * C2d));
    const float ns_k = (float)C2d;

    cvt_all<<<8192, 256, 0, stream>>>(Xq, Xk, Xv, Wq, Wk, Wv, Wp, W16, X16);

    // fused q-proj + k-proj + vT (768 blocks)
    gemm_qkv<<<768, 256, 0, stream>>>(X16, W16, qb, vTb, q2c2, qsc, ns_q, ns_k);

    attn<<<dim3(16, 64), 256, 0, stream>>>(qb, kb, vTb, q2c2, k2c2, attnout);

    gemm_fin<<<512, 256, 0, stream>>>(attnout, W16 + 3 * (1u << 20), out, bp);
}

// Round 17
// 103.302 us; speedup vs baseline: 1.1620x; 1.0419x over previous
//
#include <hip/hip_runtime.h>

// MultiHeadAttentionForViTDiscriminator: B=4, C=1024, D=1024, H=16, DH=64
// R17: exact restore of R14 (verified best: 102.8us). R15 (2-phase dbuf) and
//      R16 (distance-2 reg banks) both regressed -- source-level pipelining on
//      this structure is null/negative (matches guide m131-m141); compiler
//      re-sinks loads regardless (R16 VGPR=80 proved banks weren't kept live).
//      Components: R10-verified gemm128 inner loop; R14 L2 maps (qk z=bid&1
//      XCD-specialized, vT chunked -- FETCH 58.5->28.8MB validated); R13 attn
//      structure (1024 blocks, 64 q-rows, 33KB LDS) + R14 ILP hoists.
// Workspace (64 MB):
//   [0,8M) W16  [8,32M) X16 (Xq|Xk|Xv f16)  [32,40M) qb  [40,48M) kb
//   [48,56M) vTb  [56,64M) attnout
//   norms q2c2/k2c2 (2 x 256KB f32) live in d_out's head (dead before final GEMM).

typedef _Float16 f16;
typedef __attribute__((ext_vector_type(2))) _Float16 f16x2;
typedef __attribute__((ext_vector_type(8))) _Float16 f16x8;
typedef __attribute__((ext_vector_type(4))) float f32x4;
typedef __attribute__((ext_vector_type(16))) float f32x16;

#define MFMA16(a, b, c) __builtin_amdgcn_mfma_f32_16x16x32_f16((a), (b), (c), 0, 0, 0)
#define MFMA32(a, b, c) __builtin_amdgcn_mfma_f32_32x32x16_f16((a), (b), (c), 0, 0, 0)

constexpr double LOG2E = 1.4426950408889634;
constexpr double C2d = 0.015625 * LOG2E * LOG2E;  // (DH^-0.5 * log2e)^2

#if __has_builtin(__builtin_amdgcn_exp2f)
#define EXP2F(x) __builtin_amdgcn_exp2f(x)
#else
#define EXP2F(x) exp2f(x)
#endif
#if __has_builtin(__builtin_amdgcn_sqrtf)
#define SQRTF(x) __builtin_amdgcn_sqrtf(x)
#else
#define SQRTF(x) sqrtf(x)
#endif

__device__ __forceinline__ void stage16(const void* g, void* lds_base_uniform) {
#if __has_builtin(__builtin_amdgcn_global_load_lds)
    __builtin_amdgcn_global_load_lds((const __attribute__((address_space(1))) void*)g,
                                     (__attribute__((address_space(3))) void*)lds_base_uniform,
                                     16, 0, 0);
#else
    const int lane = threadIdx.x & 63;
    *(f16x8*)((f16*)lds_base_uniform + lane * 8) = *(const f16x8*)g;
#endif
}

__device__ __forceinline__ f16x8 cvt8v(f32x4 a, f32x4 b) {
    f16x8 o;
    o[0] = (f16)a[0]; o[1] = (f16)a[1]; o[2] = (f16)a[2]; o[3] = (f16)a[3];
    o[4] = (f16)b[0]; o[5] = (f16)b[1]; o[6] = (f16)b[2]; o[7] = (f16)b[3];
    return o;
}

// One conversion kernel for all fp32->f16 inputs. 8192 blocks x 2048 elems = 16M.
__global__ __launch_bounds__(256) void cvt_all(const float* __restrict__ Xq,
                                               const float* __restrict__ Xk,
                                               const float* __restrict__ Xv,
                                               const float* __restrict__ Wq,
                                               const float* __restrict__ Wk,
                                               const float* __restrict__ Wv,
                                               const float* __restrict__ Wp,
                                               f16* __restrict__ W16,
                                               f16* __restrict__ X16) {
    const size_t idx = (size_t)blockIdx.x * 2048 + threadIdx.x * 8;
    const size_t M4 = 4ull << 20, M1 = 1ull << 20;
    const float* s;
    f16* d;
    if (idx < 3 * M4) {
        if (idx < M4) s = Xq + idx;
        else if (idx < 2 * M4) s = Xk + (idx - M4);
        else s = Xv + (idx - 2 * M4);
        d = X16 + idx;
    } else {
        size_t wi = idx - 3 * M4;
        if (wi < M1) s = Wq + wi;
        else if (wi < 2 * M1) s = Wk + (wi - M1);
        else if (wi < 3 * M1) s = Wv + (wi - 2 * M1);
        else s = Wp + (wi - 3 * M1);
        d = W16 + wi;
    }
    f32x4 a = *(const f32x4*)s;
    f32x4 b = *(const f32x4*)(s + 4);
    *(f16x8*)d = cvt8v(a, b);
}

// 128x128 GEMM body (R10-verified): BK=64, 4 waves (2x2), 64x64 wave tile,
// MFMA32, XOR-swizzled LDS via pre-swizzled gload_lds source.
template <bool NORMS, bool F32OUT>
__device__ __forceinline__ void gemm128(f16* As, f16* Bs,
                                        const f16* __restrict__ Ap,
                                        const f16* __restrict__ Bp,
                                        f16* __restrict__ Cop,
                                        float* __restrict__ Cf,
                                        const float* __restrict__ bias,
                                        float* __restrict__ nrmp,
                                        float osc, float nscale,
                                        int row0, int col0, int N, int K) {
    const int tid = threadIdx.x;
    const int lane = tid & 63;
    const int w = tid >> 6;
    const int l31 = lane & 31, l5 = lane >> 5;
    const int wr = (w >> 1) * 64, wc = (w & 1) * 64;

    f32x16 acc[2][2] = {};

    for (int kt = 0; kt < K; kt += 64) {
        __syncthreads();
#pragma unroll
        for (int t = 0; t < 4; ++t) {
            const int rb = w * 32 + t * 8;
            const int rr = rb + (lane >> 3);
            const int gs = (lane & 7) ^ (rr & 7);
            stage16(&Ap[(size_t)(row0 + rr) * K + kt + gs * 8], &As[rb * 64]);
            stage16(&Bp[(size_t)(col0 + rr) * K + kt + gs * 8], &Bs[rb * 64]);
        }
        __syncthreads();
#pragma unroll
        for (int ks = 0; ks < 4; ++ks) {
            const int gq = ks * 2 + l5;
            f16x8 af[2], bf[2];
#pragma unroll
            for (int mr = 0; mr < 2; ++mr)
                af[mr] = *(const f16x8*)&As[(wr + mr * 32 + l31) * 64 + ((gq ^ (l31 & 7)) * 8)];
#pragma unroll
            for (int n2 = 0; n2 < 2; ++n2)
                bf[n2] = *(const f16x8*)&Bs[(wc + n2 * 32 + l31) * 64 + ((gq ^ (l31 & 7)) * 8)];
#pragma unroll
            for (int mr = 0; mr < 2; ++mr)
#pragma unroll
                for (int n2 = 0; n2 < 2; ++n2) acc[mr][n2] = MFMA32(af[mr], bf[n2], acc[mr][n2]);
        }
    }

    const int cc0 = col0 + wc + l31;
    const int cc1 = col0 + wc + 32 + l31;
    const int hh = (col0 + wc) >> 6;
#pragma unroll
    for (int mr = 0; mr < 2; ++mr)
#pragma unroll
        for (int j = 0; j < 16; ++j) {
            const int rr = row0 + wr + mr * 32 + (j & 3) + 8 * (j >> 2) + 4 * l5;
            if (F32OUT) {
                Cf[(size_t)rr * N + cc0] = acc[mr][0][j] + bias[cc0];
                Cf[(size_t)rr * N + cc1] = acc[mr][1][j] + bias[cc1];
            } else {
                const f16 h0 = (f16)(acc[mr][0][j] * osc);
                const f16 h1 = (f16)(acc[mr][1][j] * osc);
                if (NORMS) {
                    float v0 = (float)h0, v1 = (float)h1;
                    float s = v0 * v0 + v1 * v1;
                    s += __shfl_xor(s, 1);
                    s += __shfl_xor(s, 2);
                    s += __shfl_xor(s, 4);
                    s += __shfl_xor(s, 8);
                    s += __shfl_xor(s, 16);
                    if (l31 == 0)
                        nrmp[(size_t)((rr >> 10) * 16 + hh) * 1024 + (rr & 1023)] = s * nscale;
                }
                Cop[(size_t)rr * N + cc0] = h0;
                Cop[(size_t)rr * N + cc1] = h1;
            }
        }
}

// Fused qk + vT launch with XCD-aware mappings (dispatch round-robins bid%8):
//   qk (bid<512): z = bid&1 -> each XCD runs only q or k (4MB/XCD <= L2).
//   vT (bid>=512): 4 token-col strips x all 8 Wv rows per XCD (3MB <= L2).
__global__ __launch_bounds__(256, 2) void gemm_qkv(const f16* __restrict__ X16,
                                                   const f16* __restrict__ W16,
                                                   f16* __restrict__ qb_base,
                                                   f16* __restrict__ vTb,
                                                   float* __restrict__ nrm,
                                                   float qsc, float ns_q, float ns_k) {
    __shared__ __attribute__((aligned(16))) f16 As[128 * 64];
    __shared__ __attribute__((aligned(16))) f16 Bs[128 * 64];
    const int bid = blockIdx.x;
    if (bid < 512) {
        const int z = bid & 1;
        const int t = (((bid & 7) >> 1) << 6) | (bid >> 3);  // bijective per z
        const int row0 = (t >> 3) * 128;
        const int col0 = (t & 7) * 128;
        gemm128<true, false>(As, Bs,
                             X16 + (size_t)z * (4u << 20), W16 + (size_t)z * (1u << 20),
                             qb_base + (size_t)z * (4u << 20), nullptr, nullptr,
                             nrm + (size_t)z * 65536,
                             z ? 1.0f : qsc, z ? ns_k : ns_q, row0, col0, 1024, 1024);
    } else {
        const int f2 = bid - 512;
        const int x = f2 & 7, j = f2 >> 3;
        const int col0 = (x * 4 + (j & 3)) * 128;
        const int row0 = (j >> 2) * 128;
        gemm128<false, false>(As, Bs,
                              W16 + 2 * (1u << 20), X16 + 2 * (4u << 20),
                              vTb, nullptr, nullptr, nullptr,
                              1.0f, 0.f, row0, col0, 4096, 1024);
    }
}

// Final projection: 64x128 tiles, 512 blocks (2/CU). f32 out + bias.
__global__ __launch_bounds__(256, 2) void gemm_fin(const f16* __restrict__ A,
                                                   const f16* __restrict__ B,
                                                   float* __restrict__ Cf,
                                                   const float* __restrict__ bias) {
    __shared__ __attribute__((aligned(16))) f16 As[64 * 64];
    __shared__ __attribute__((aligned(16))) f16 Bs[128 * 64];
    const int tid = threadIdx.x;
    const int lane = tid & 63;
    const int w = tid >> 6;
    const int l31 = lane & 31, l5 = lane >> 5;
    const int wr = (w & 1) * 32, wc = (w >> 1) * 64;
    const int f = blockIdx.x;
    const int g = (f & 7) * 64 + (f >> 3);
    const int row0 = (g >> 3) * 64, col0 = (g & 7) * 128;
    const int K = 1024, N = 1024;

    f32x16 acc[2] = {};

    for (int kt = 0; kt < K; kt += 64) {
        __syncthreads();
#pragma unroll
        for (int t = 0; t < 2; ++t) {  // A: 64 rows
            const int rb = w * 16 + t * 8;
            const int rr = rb + (lane >> 3);
            const int gs = (lane & 7) ^ (rr & 7);
            stage16(&A[(size_t)(row0 + rr) * K + kt + gs * 8], &As[rb * 64]);
        }
#pragma unroll
        for (int t = 0; t < 4; ++t) {  // B: 128 rows
            const int rb = w * 32 + t * 8;
            const int rr = rb + (lane >> 3);
            const int gs = (lane & 7) ^ (rr & 7);
            stage16(&B[(size_t)(col0 + rr) * K + kt + gs * 8], &Bs[rb * 64]);
        }
        __syncthreads();
#pragma unroll
        for (int ks = 0; ks < 4; ++ks) {
            const int gq = ks * 2 + l5;
            f16x8 af = *(const f16x8*)&As[(wr + l31) * 64 + ((gq ^ (l31 & 7)) * 8)];
#pragma unroll
            for (int n2 = 0; n2 < 2; ++n2) {
                f16x8 bf = *(const f16x8*)&Bs[(wc + n2 * 32 + l31) * 64 + ((gq ^ (l31 & 7)) * 8)];
                acc[n2] = MFMA32(af, bf, acc[n2]);
            }
        }
    }

    const int cc0 = col0 + wc + l31;
    const int cc1 = col0 + wc + 32 + l31;
#pragma unroll
    for (int j = 0; j < 16; ++j) {
        const int rr = row0 + wr + (j & 3) + 8 * (j >> 2) + 4 * l5;
        Cf[(size_t)rr * N + cc0] = acc[0][j] + bias[cc0];
        Cf[(size_t)rr * N + cc1] = acc[1][j] + bias[cc1];
    }
}

// Distance attention: 1024 blocks x 256 threads, 64 q-rows/block (4 waves x 16),
// full-K loop. Swapped QK + permuted K slots => in-reg P; den via ones-MFMA.
// K-frag ping-pong prefetch + V-frags hoisted above the trans chain (R14).
__global__ __launch_bounds__(256, 2) void attn(const f16* __restrict__ qs,
                                               const f16* __restrict__ kb,
                                               const f16* __restrict__ vT,
                                               const float* __restrict__ q2c2,
                                               const float* __restrict__ k2c2,
                                               f16* __restrict__ out) {
    __shared__ __attribute__((aligned(16))) f16 Ks[128 * 64];  // permuted slots + XOR swizzle
    __shared__ __attribute__((aligned(16))) f16 Vs[64 * 128];  // XOR-swizzled
    __shared__ float k2tile[128];                              // linear (keyed by true k)
    const int tid = threadIdx.x;
    const int lane = tid & 63;
    const int w = tid >> 6;
    const int l15 = lane & 15, l4 = lane >> 4;
    const int fid = blockIdx.y * 16 + blockIdx.x;
    const int qt = (fid >> 3) & 15;
    const int bh = (fid & 7) * 8 + (fid >> 7);
    const int b = bh >> 4, h = bh & 15;
    const int wq = w * 16;
    const int hcol = h * 64;
    const int qrow0 = b * 1024 + qt * 64;
    const f16* vTh = vT + (size_t)hcol * 4096 + b * 1024;  // vT[d=1024][tok=4096]

    const int sr = tid >> 3, sc0 = (tid & 7) * 8;   // K staging (keys sr+i*32)
    const int vr = tid >> 4, vc0 = (tid & 15) * 8;  // V staging (rows vr+j*16)
    const int vsw = (vr & 7) << 3;
    const int fsw = (l15 & 7) << 3;                 // fragment-read swizzle

    f16x8 bq[2];
#pragma unroll
    for (int ks = 0; ks < 2; ++ks)
        bq[ks] = *(const f16x8*)&qs[(size_t)(qrow0 + wq + l15) * 1024 + hcol + ks * 32 + l4 * 8];
    const float q2m = q2c2[(size_t)bh * 1024 + qt * 64 + wq + l15];

    f32x4 accv[4] = {};
    f32x4 dacc = {};
    const f16 one = (f16)1.f;
    const f16x8 ones8 = {one, one, one, one, one, one, one, one};

    f16x8 kreg[4], vreg[4];
    float k2reg = 0.f;
#define ISSUE_LOADS(KT)                                                                                      \
    {                                                                                                        \
        _Pragma("unroll") for (int i = 0; i < 4; ++i)                                                        \
            kreg[i] = *(const f16x8*)&kb[(size_t)(b * 1024 + (KT) * 128 + sr + i * 32) * 1024 + hcol + sc0]; \
        _Pragma("unroll") for (int j = 0; j < 4; ++j)                                                        \
            vreg[j] = *(const f16x8*)&vTh[(size_t)(vr + j * 16) * 4096 + (KT) * 128 + vc0];                  \
        k2reg = (tid < 128) ? k2c2[(size_t)bh * 1024 + (KT) * 128 + tid] : 0.f;                              \
    }

    ISSUE_LOADS(0)

    for (int kt = 0; kt < 8; ++kt) {
        __syncthreads();
#pragma unroll
        for (int i = 0; i < 4; ++i) {
            const int kap = sr + i * 32;
            const int s = ((kap >> 5) & 3) * 32 + ((kap >> 2) & 1) * 16 + ((kap >> 3) & 3) * 4 + (kap & 3);
            *(f16x8*)&Ks[s * 64 + (sc0 ^ ((s & 7) << 3))] = kreg[i];
        }
#pragma unroll
        for (int j = 0; j < 4; ++j) *(f16x8*)&Vs[(vr + j * 16) * 128 + (vc0 ^ vsw)] = vreg[j];
        if (tid < 128) k2tile[tid] = k2reg;
        __syncthreads();
        if (kt < 7) ISSUE_LOADS(kt + 1)  // global prefetch hides under compute

        // K-frag ping-pong: preload kk=0's two windows
        f16x8 kfb[2][4];
#pragma unroll
        for (int hh = 0; hh < 2; ++hh) {
            kfb[0][hh * 2] = *(const f16x8*)&Ks[(hh * 16 + l15) * 64 + ((l4 * 8) ^ fsw)];
            kfb[0][hh * 2 + 1] = *(const f16x8*)&Ks[(hh * 16 + l15) * 64 + ((32 + l4 * 8) ^ fsw)];
        }
#pragma unroll
        for (int kk = 0; kk < 4; ++kk) {
            const int cb = kk & 1;
            if (kk < 3) {  // prefetch next window-pair's K frags
#pragma unroll
                for (int hh = 0; hh < 2; ++hh) {
                    const int n_ = (kk + 1) * 2 + hh;
                    kfb[cb ^ 1][hh * 2] = *(const f16x8*)&Ks[(n_ * 16 + l15) * 64 + ((l4 * 8) ^ fsw)];
                    kfb[cb ^ 1][hh * 2 + 1] = *(const f16x8*)&Ks[(n_ * 16 + l15) * 64 + ((32 + l4 * 8) ^ fsw)];
                }
            }
            // V frags issued BEFORE the trans chain (latency hides under it)
            f16x8 vf[4];
#pragma unroll
            for (int n2 = 0; n2 < 4; ++n2)
                vf[n2] = *(const f16x8*)&Vs[(n2 * 16 + l15) * 128 + ((kk * 32 + l4 * 8) ^ fsw)];

            unsigned um[4];
#pragma unroll
            for (int half = 0; half < 2; ++half) {
                f32x4 k2q = *(const f32x4*)&k2tile[kk * 32 + l4 * 8 + half * 4];
                f32x4 c0;
#pragma unroll
                for (int r = 0; r < 4; ++r) c0[r] = q2m + k2q[r];
                f32x4 st = MFMA16(kfb[cb][half * 2], bq[0], c0);
                st = MFMA16(kfb[cb][half * 2 + 1], bq[1], st);
                float p0 = EXP2F(SQRTF(fmaxf(st[0], 0.f)));
                float p1 = EXP2F(SQRTF(fmaxf(st[1], 0.f)));
                float p2 = EXP2F(SQRTF(fmaxf(st[2], 0.f)));
                float p3 = EXP2F(SQRTF(fmaxf(st[3], 0.f)));
                f16x2 lo = {(f16)p0, (f16)p1};
                f16x2 hi = {(f16)p2, (f16)p3};
                um[half * 2] = __builtin_bit_cast(unsigned, lo);
                um[half * 2 + 1] = __builtin_bit_cast(unsigned, hi);
            }
            uint4 u = {um[0], um[1], um[2], um[3]};
            f16x8 ap = __builtin_bit_cast(f16x8, u);
            dacc = MFMA16(ap, ones8, dacc);
#pragma unroll
            for (int n2 = 0; n2 < 4; ++n2) accv[n2] = MFMA16(ap, vf[n2], accv[n2]);
        }
    }

#pragma unroll
    for (int r = 0; r < 4; ++r) {
        const float rd = 1.0f / dacc[r];
#pragma unroll
        for (int n2 = 0; n2 < 4; ++n2)
            out[(size_t)(qrow0 + wq + l4 * 4 + r) * 1024 + hcol + n2 * 16 + l15] =
                (f16)(accv[n2][r] * rd);
    }
}

extern "C" void kernel_launch(void* const* d_in, const int* in_sizes, int n_in,
                              void* d_out, int out_size, void* d_ws, size_t ws_size,
                              hipStream_t stream) {
    const float* Xq = (const float*)d_in[0];
    const float* Xk = (const float*)d_in[1];
    const float* Xv = (const float*)d_in[2];
    const float* Wq = (const float*)d_in[3];
    const float* Wk = (const float*)d_in[4];
    const float* Wv = (const float*)d_in[5];
    const float* Wp = (const float*)d_in[6];
    const float* bp = (const float*)d_in[7];
    float* out = (float*)d_out;

    char* ws = (char*)d_ws;
    f16* W16 = (f16*)(ws);                      // 4M f16
    f16* X16 = (f16*)(ws + (8ull << 20));       // Xq16|Xk16|Xv16
    f16* qb = (f16*)(ws + (32ull << 20));       // qk out base (z-stride 4M f16)
    f16* kb = (f16*)(ws + (40ull << 20));
    f16* vTb = (f16*)(ws + (48ull << 20));
    f16* attnout = (f16*)(ws + (56ull << 20));
    (void)kb;
    // norms scratch in d_out head; written each launch before use, overwritten by final GEMM
    float* q2c2 = out;
    float* k2c2 = out + 65536;

    const float qsc = (float)(-2.0 * C2d);
    const float ns_q = (float)(1.0 / (4.0 * C2d));
    const float ns_k = (float)C2d;

    cvt_all<<<8192, 256, 0, stream>>>(Xq, Xk, Xv, Wq, Wk, Wv, Wp, W16, X16);

    // fused q-proj + k-proj + vT (768 blocks)
    gemm_qkv<<<768, 256, 0, stream>>>(X16, W16, qb, vTb, q2c2, qsc, ns_q, ns_k);

    attn<<<dim3(16, 64), 256, 0, stream>>>(qb, kb, vTb, q2c2, k2c2, attnout);

    gemm_fin<<<512, 256, 0, stream>>>(attnout, W16 + 3 * (1u << 20), out, bp);
}